// Round 1
// baseline (253.658 us; speedup 1.0000x reference)
//
#include <hip/hip_runtime.h>

// ExtractPatchesPositionLayer — bilinear patch extraction.
// out[b,i,j,c] = bilinear(img[b], y = i+32+oy[b,c], x = j+32+ox[b,c])
// Since i+32 is integer, floor/frac of the sample coordinate splits into
// (i+32+floor(oy)) and frac(oy): the 4 bilinear weights are CONSTANT per
// (b,c). Positions are bounded by +/-20 (SHIFT_MAX), c0=32, so all gather
// indices lie in [12,116] subset [0,128): the reference's out-of-bounds
// zero path is never taken -> unconditional gathers are exact.

constexpr int Mdim   = 128;  // padded image side
constexpr int Npatch = 64;   // output patch side
constexpr int Cc     = 4;    // channels (position candidates)
constexpr int C0     = 32;   // (M - N) / 2

__global__ __launch_bounds__(256) void extract_patches_kernel(
    const float* __restrict__ img,   // [B, M, M]
    const float* __restrict__ pos,   // [B, 1, 2, C] : [b][axis][c], axis0=x, axis1=y
    float* __restrict__ out)         // [B, N, N, C]
{
    const int b = blockIdx.x;
    const float* __restrict__ imgb = img + (size_t)b * (Mdim * Mdim);
    const float* __restrict__ pb   = pos + (size_t)b * (2 * Cc);

    // Per-(b,c) constants — computed redundantly per thread (cheap, same
    // address across lanes -> broadcast loads; avoids LDS + barrier).
    float w00[Cc], w01[Cc], w10[Cc], w11[Cc];
    int   ixv[Cc], iyv[Cc];
#pragma unroll
    for (int c = 0; c < Cc; ++c) {
        const float ox = pb[c];
        const float oy = pb[Cc + c];
        const float fx = floorf(ox);
        const float fy = floorf(oy);
        const float wx = ox - fx;
        const float wy = oy - fy;
        ixv[c] = C0 + (int)fx;
        iyv[c] = C0 + (int)fy;
        w00[c] = (1.0f - wy) * (1.0f - wx);
        w01[c] = (1.0f - wy) * wx;
        w10[c] = wy * (1.0f - wx);
        w11[c] = wy * wx;
    }

    const int tid = threadIdx.x;
    const int j  = tid & (Npatch - 1);   // column 0..63 (lane-contiguous)
    const int i0 = tid >> 6;             // row phase 0..3

    for (int i = i0; i < Npatch; i += 4) {
        float4 o;
        float* res = reinterpret_cast<float*>(&o);
#pragma unroll
        for (int c = 0; c < Cc; ++c) {
            const float* p = imgb + (iyv[c] + i) * Mdim + ixv[c] + j;
            const float v00 = p[0];
            const float v01 = p[1];
            const float v10 = p[Mdim];
            const float v11 = p[Mdim + 1];
            res[c] = w00[c] * v00 + w01[c] * v01 + w10[c] * v10 + w11[c] * v11;
        }
        // out[b,i,j,c] with c fastest -> one aligned float4 per (i,j); lanes
        // j, j+1 store 16B apart -> fully coalesced 1 KiB/wave store.
        float4* optr = reinterpret_cast<float4*>(
            out + (((size_t)b * Npatch + i) * Npatch + j) * Cc);
        *optr = o;
    }
}

extern "C" void kernel_launch(void* const* d_in, const int* in_sizes, int n_in,
                              void* d_out, int out_size, void* d_ws, size_t ws_size,
                              hipStream_t stream) {
    const float* img = (const float*)d_in[0];  // padded_obj [2048,128,128,1] f32
    const float* pos = (const float*)d_in[1];  // positions  [2048,1,2,4]   f32
    float* out = (float*)d_out;                // [2048,64,64,4] f32

    const int B = in_sizes[0] / (Mdim * Mdim); // 2048
    extract_patches_kernel<<<dim3(B), dim3(256), 0, stream>>>(img, pos, out);
}

// Round 2
// 232.441 us; speedup vs baseline: 1.0913x; 1.0913x over previous
//
#include <hip/hip_runtime.h>

// ExtractPatchesPositionLayer — bilinear patch extraction, LDS-staged.
// out[b,i,j,c] = bilinear(img[b], y = i+32+oy[b,c], x = j+32+ox[b,c])
// floor(i+32+oy) = i+32+floor(oy): the 4 bilinear weights are constant per
// (b,c). positions in [-20,20) => integer tap coords in [12,115] always
// in-bounds; the reference's OOB-zero path is never taken.
//
// R1 showed 88us at 25% HBM, VALUBusy 9%: gather traffic (537 MB aggregate)
// thrashes L1 (64KB/block vs 32KB) and L2 (16MB concurrent working set vs
// 4MB/XCD) -> L3-latency-bound. Fix: stage rows 12..115 (52 KB) in LDS once
// per block via global_load_lds width=16 (contiguous copy), serve taps from
// LDS (lane-consecutive -> conflict-free).

constexpr int Mdim   = 128;  // padded image side
constexpr int Npatch = 64;   // output patch side
constexpr int Cc     = 4;    // channels
constexpr int C0     = 32;   // (M - N) / 2
constexpr int ROW0   = 12;   // first row/col ever touched (C0 - 20)
constexpr int NROWS  = 104;  // rows 12..115 inclusive

__global__ __launch_bounds__(512) void extract_patches_kernel(
    const float* __restrict__ img,   // [B, M, M]
    const float* __restrict__ pos,   // [B, 1, 2, C]: axis0=x, axis1=y
    float* __restrict__ out)         // [B, N, N, C]
{
    __shared__ float lds[NROWS * Mdim];  // 52 KB -> 3 blocks/CU, 24 waves/CU

    const int b = blockIdx.x;
    const float* __restrict__ imgb = img + (size_t)b * (Mdim * Mdim);
    const float* __restrict__ pb   = pos + (size_t)b * (2 * Cc);

    const int tid  = threadIdx.x;
    const int lane = tid & 63;
    const int wave = tid >> 6;           // 0..7

    // ---- Stage rows 12..115 (contiguous 53248 B) into LDS ----
    // global_load_lds: per-lane global addr, wave-uniform LDS base + lane*16.
    // 52 chunks of 1 KiB (64 lanes x 16 B); 8 waves round-robin.
    const float* src = imgb + ROW0 * Mdim;
    for (int w = wave; w < (NROWS * Mdim) / 256; w += 8) {
        const float* g = src + w * 256 + lane * 4;
        __builtin_amdgcn_global_load_lds(
            (const __attribute__((address_space(1))) void*)g,
            (__attribute__((address_space(3))) void*)&lds[w * 256],
            16, 0, 0);
    }

    // ---- Per-(b,c) constants (redundant per thread; broadcast loads) ----
    float w00[Cc], w01[Cc], w10[Cc], w11[Cc];
    int   base0[Cc];
#pragma unroll
    for (int c = 0; c < Cc; ++c) {
        const float ox = pb[c];
        const float oy = pb[Cc + c];
        const float fx = floorf(ox);
        const float fy = floorf(oy);
        const float wx = ox - fx;
        const float wy = oy - fy;
        const int ix = C0 + (int)fx;     // in [12, 51]
        const int iy = C0 + (int)fy;     // in [12, 51]
        base0[c] = (iy - ROW0) * Mdim + ix;
        w00[c] = (1.0f - wy) * (1.0f - wx);
        w01[c] = (1.0f - wy) * wx;
        w10[c] = wy * (1.0f - wx);
        w11[c] = wy * wx;
    }

    __syncthreads();   // drains vmcnt(0): staged data visible

    const int j  = tid & (Npatch - 1);   // column 0..63 (lane-contiguous)
    const int i0 = tid >> 6;             // row phase 0..7

    for (int i = i0; i < Npatch; i += 8) {
        float4 o;
        float* res = reinterpret_cast<float*>(&o);
#pragma unroll
        for (int c = 0; c < Cc; ++c) {
            const int base = base0[c] + i * Mdim + j;
            const float v00 = lds[base];
            const float v01 = lds[base + 1];
            const float v10 = lds[base + Mdim];
            const float v11 = lds[base + Mdim + 1];
            res[c] = w00[c] * v00 + w01[c] * v01 + w10[c] * v10 + w11[c] * v11;
        }
        float4* optr = reinterpret_cast<float4*>(
            out + (((size_t)b * Npatch + i) * Npatch + j) * Cc);
        *optr = o;
    }
}

extern "C" void kernel_launch(void* const* d_in, const int* in_sizes, int n_in,
                              void* d_out, int out_size, void* d_ws, size_t ws_size,
                              hipStream_t stream) {
    const float* img = (const float*)d_in[0];  // padded_obj [2048,128,128,1] f32
    const float* pos = (const float*)d_in[1];  // positions  [2048,1,2,4]   f32
    float* out = (float*)d_out;                // [2048,64,64,4] f32

    const int B = in_sizes[0] / (Mdim * Mdim); // 2048
    extract_patches_kernel<<<dim3(B), dim3(512), 0, stream>>>(img, pos, out);
}

// Round 3
// 231.812 us; speedup vs baseline: 1.0942x; 1.0027x over previous
//
#include <hip/hip_runtime.h>

// ExtractPatchesPositionLayer — bilinear patch extraction, R3.
// out[b,i,j,c] = bilinear(img[b], y = i+32+oy[b,c], x = j+32+ox[b,c])
// floor(i+32+oy) = i+32+floor(oy): weights constant per (b,c); tap coords
// always in [12,116] (positions bounded by SHIFT_MAX=20) -> reference's
// OOB-zero path never taken.
//
// R2 (~67us): full-batch blocks, 52KB LDS (3 blocks/CU), 4 scalar LDS taps
// per output -> LDS-instr + overlap limited. R3:
//  * 2 blocks per batch (32 output rows each): staged window <= 74 rows
//    (iy span <= 39, +33, clamped in-bounds) = 37KB LDS -> 4 blocks/CU,
//    32 waves/CU (full occupancy).
//  * rolling-row reuse: thread owns 4 CONSECUTIVE rows; tap row i+1 is
//    reused as next output's top row -> 2 LDS dwords per output (adjacent
//    pair -> ds_read2_b32) instead of 4.

constexpr int Mdim   = 128;  // padded image side
constexpr int Npatch = 64;   // output patch side
constexpr int Cc     = 4;    // channels
constexpr int C0     = 32;   // (M - N) / 2
constexpr int SROWS  = 74;   // staged rows per block (37888 B of LDS)

__global__ __launch_bounds__(512, 8) void extract_patches_kernel(
    const float* __restrict__ img,   // [B, M, M]
    const float* __restrict__ pos,   // [B, 1, 2, C]: axis0=x, axis1=y
    float* __restrict__ out)         // [B, N, N, C]
{
    __shared__ float lds[SROWS * Mdim];  // 37 KiB -> 4 blocks/CU

    const int bid  = blockIdx.x;
    const int b    = bid >> 1;
    const int h    = bid & 1;            // row-half: output rows [32h, 32h+32)
    const float* __restrict__ imgb = img + (size_t)b * (Mdim * Mdim);
    const float* __restrict__ pb   = pos + (size_t)b * (2 * Cc);

    const int tid  = threadIdx.x;
    const int lane = tid & 63;
    const int wave = tid >> 6;           // 0..7

    // ---- Per-(b,c) constants (uniform across threads; broadcast loads) ----
    float w00[Cc], w01[Cc], w10[Cc], w11[Cc];
    int   iyv[Cc], ixv[Cc];
#pragma unroll
    for (int c = 0; c < Cc; ++c) {
        const float ox = pb[c];
        const float oy = pb[Cc + c];
        const float fx = floorf(ox);
        const float fy = floorf(oy);
        const float wx = ox - fx;
        const float wy = oy - fy;
        ixv[c] = C0 + (int)fx;           // in [12, 51]
        iyv[c] = C0 + (int)fy;           // in [12, 51]
        w00[c] = (1.0f - wy) * (1.0f - wx);
        w01[c] = (1.0f - wy) * wx;
        w10[c] = wy * (1.0f - wx);
        w11[c] = wy * wx;
    }

    // Staged window start: covers rows [min_iy+32h, max_iy+32h+33]
    // (span<=39 -> fits in 74 rows); clamp so r0+73 <= 127 (in-bounds).
    int min_iy = min(min(iyv[0], iyv[1]), min(iyv[2], iyv[3]));
    int r0 = min(min_iy + 32 * h, Mdim - SROWS);   // <= 54

    // ---- Stage rows r0..r0+73 (37888 B contiguous) into LDS ----
    // 37 chunks of 1 KiB (64 lanes x 16 B), 8 waves round-robin.
    const float* src = imgb + r0 * Mdim;
    for (int w = wave; w < (SROWS * Mdim) / 256; w += 8) {
        const float* g = src + w * 256 + lane * 4;
        __builtin_amdgcn_global_load_lds(
            (const __attribute__((address_space(1))) void*)g,
            (__attribute__((address_space(3))) void*)&lds[w * 256],
            16, 0, 0);
    }

    __syncthreads();   // drains vmcnt(0): staged data visible

    const int j   = tid & 63;            // column 0..63
    const int s   = tid >> 6;            // strip 0..7
    const int li0 = s * 4;               // local rows li0..li0+3

    // Rolling state per channel: top-row tap pair (v00,v01).
    int   a[Cc];
    float p0[Cc], p1[Cc];
#pragma unroll
    for (int c = 0; c < Cc; ++c) {
        a[c] = (iyv[c] + 32 * h + li0 - r0) * Mdim + ixv[c] + j;
        p0[c] = lds[a[c]];
        p1[c] = lds[a[c] + 1];           // adjacent pair -> ds_read2_b32
    }

    float* obase = out + (((size_t)b * Npatch + 32 * h + li0) * Npatch + j) * Cc;
#pragma unroll
    for (int k = 0; k < 4; ++k) {
        float4 o;
        float* res = reinterpret_cast<float*>(&o);
#pragma unroll
        for (int c = 0; c < Cc; ++c) {
            a[c] += Mdim;
            const float n0 = lds[a[c]];
            const float n1 = lds[a[c] + 1];
            res[c] = w00[c] * p0[c] + w01[c] * p1[c] + w10[c] * n0 + w11[c] * n1;
            p0[c] = n0;
            p1[c] = n1;
        }
        *reinterpret_cast<float4*>(obase + (size_t)k * Npatch * Cc) = o;
    }
}

extern "C" void kernel_launch(void* const* d_in, const int* in_sizes, int n_in,
                              void* d_out, int out_size, void* d_ws, size_t ws_size,
                              hipStream_t stream) {
    const float* img = (const float*)d_in[0];  // padded_obj [B,128,128,1] f32
    const float* pos = (const float*)d_in[1];  // positions  [B,1,2,4]   f32
    float* out = (float*)d_out;                // [B,64,64,4] f32

    const int B = in_sizes[0] / (Mdim * Mdim); // 2048
    extract_patches_kernel<<<dim3(2 * B), dim3(512), 0, stream>>>(img, pos, out);
}